// Round 1
// baseline (494.120 us; speedup 1.0000x reference)
//
#include <hip/hip_runtime.h>

// CARAFE3D: C1=32, CM=8, C2=16, K=3 (k3=27), R=2 (r3=8), CK=216
// N=2, H=W=D=32, HWD=32768, out (2,16,64,64,64) fp32

__global__ __launch_bounds__(256) void down_out_kernel(
    const float* __restrict__ x, const float* __restrict__ w_down,
    const float* __restrict__ b_down, const float* __restrict__ w_out,
    float* __restrict__ t, float* __restrict__ xo) {
  int idx = blockIdx.x * 256 + threadIdx.x;   // 0..65535
  int n = idx >> 15;
  int p = idx & 32767;
  const float* xp = x + ((size_t)n << 20) + p;  // n*32*32768
  float at[8];
  float ao[16];
#pragma unroll
  for (int m = 0; m < 8; ++m) at[m] = b_down[m];
#pragma unroll
  for (int o = 0; o < 16; ++o) ao[o] = 0.f;
#pragma unroll
  for (int c = 0; c < 32; ++c) {
    float xv = xp[(size_t)c << 15];
#pragma unroll
    for (int m = 0; m < 8; ++m) at[m] = fmaf(xv, w_down[m * 32 + c], at[m]);
#pragma unroll
    for (int o = 0; o < 16; ++o) ao[o] = fmaf(xv, w_out[o * 32 + c], ao[o]);
  }
#pragma unroll
  for (int m = 0; m < 8; ++m) t[(((size_t)n * 8 + m) << 15) + p] = at[m];
#pragma unroll
  for (int o = 0; o < 16; ++o) xo[(((size_t)n * 16 + o) << 15) + p] = ao[o];
}

// One block per 4x4x4 coarse-voxel tile (64 voxels). 1024 blocks total.
__global__ __launch_bounds__(256) void carafe_kernel(
    const float* __restrict__ tg, const float* __restrict__ xog,
    const float* __restrict__ w_enc, const float* __restrict__ b_enc,
    const float* __restrict__ b_out, float* __restrict__ y) {
  __shared__ float t_lds[8 * 216];    // [m][z(6)][y(6)][x(6)] halo tile
  __shared__ float xo_lds[16 * 216];  // [c2][z][y][x] halo tile
  __shared__ float enc_lds[216 * 64]; // [o][voxel] -> becomes kern after softmax

  int b = blockIdx.x;
  int n = b >> 9;
  int tile = b & 511;
  int h0 = ((tile >> 6) & 7) << 2;
  int w0 = ((tile >> 3) & 7) << 2;
  int d0 = (tile & 7) << 2;
  int tid = threadIdx.x;

  // ---- phase 1: stage halo tiles (zero-padded at volume borders) ----
  for (int i = tid; i < 1728; i += 256) {
    int m = i / 216;
    int rem = i - m * 216;
    int z = rem / 36;
    int r2 = rem - z * 36;
    int yy = r2 / 6;
    int xx = r2 - yy * 6;
    int gh = h0 + z - 1, gw = w0 + yy - 1, gd = d0 + xx - 1;
    float val = 0.f;
    if ((unsigned)gh < 32u && (unsigned)gw < 32u && (unsigned)gd < 32u)
      val = tg[(((size_t)n * 8 + m) << 15) + (gh << 10) + (gw << 5) + gd];
    t_lds[i] = val;
  }
  for (int i = tid; i < 3456; i += 256) {
    int c = i / 216;
    int rem = i - c * 216;
    int z = rem / 36;
    int r2 = rem - z * 36;
    int yy = r2 / 6;
    int xx = r2 - yy * 6;
    int gh = h0 + z - 1, gw = w0 + yy - 1, gd = d0 + xx - 1;
    float val = 0.f;
    if ((unsigned)gh < 32u && (unsigned)gw < 32u && (unsigned)gd < 32u)
      val = xog[(((size_t)n * 16 + c) << 15) + (gh << 10) + (gw << 5) + gd];
    xo_lds[i] = val;
  }
  __syncthreads();

  int v = tid & 63;
  int g = __builtin_amdgcn_readfirstlane(tid >> 6);  // wave id, uniform
  int vz = v >> 4, vy = (v >> 2) & 3, vx = v & 3;
  int base = vz * 36 + vy * 6 + vx;

  // ---- phase 2: enc[o][v] = b_enc[o] + W_enc(216x216) . t_patch(v) ----
  // wave g computes o in [54g, 54g+54); w_enc reads are wave-uniform (s_load),
  // each t-patch LDS read is reused across all 54 outputs.
  {
    int o0 = g * 54;
    float acc[54];
#pragma unroll
    for (int j = 0; j < 54; ++j) acc[j] = b_enc[o0 + j];
    const float* tb = t_lds + base;
    const float* wb = w_enc + o0 * 216;
#pragma unroll 1
    for (int m = 0; m < 8; ++m) {
#pragma unroll 1
      for (int kh = 0; kh < 3; ++kh) {
        const float* tbc = tb + m * 216 + kh * 36;
        float tv0 = tbc[0], tv1 = tbc[1], tv2 = tbc[2];
        float tv3 = tbc[6], tv4 = tbc[7], tv5 = tbc[8];
        float tv6 = tbc[12], tv7 = tbc[13], tv8 = tbc[14];
        const float* wc = wb + m * 27 + kh * 9;
#pragma unroll
        for (int j = 0; j < 54; ++j) {
          const float* w9 = wc + j * 216;
          float a = acc[j];
          a = fmaf(w9[0], tv0, a);
          a = fmaf(w9[1], tv1, a);
          a = fmaf(w9[2], tv2, a);
          a = fmaf(w9[3], tv3, a);
          a = fmaf(w9[4], tv4, a);
          a = fmaf(w9[5], tv5, a);
          a = fmaf(w9[6], tv6, a);
          a = fmaf(w9[7], tv7, a);
          a = fmaf(w9[8], tv8, a);
          acc[j] = a;
        }
      }
    }
#pragma unroll
    for (int j = 0; j < 54; ++j) enc_lds[(o0 + j) * 64 + v] = acc[j];
  }
  __syncthreads();

  // ---- phase 3: softmax over k3=27 per (voxel, r); 512 pairs, 2/thread ----
#pragma unroll
  for (int pp = 0; pp < 2; ++pp) {
    int p = tid + pp * 256;
    int vv = p & 63;
    int r = p >> 6;
    float vals[27];
    float mx = -3.0e38f;
#pragma unroll
    for (int k = 0; k < 27; ++k) {
      vals[k] = enc_lds[(k * 8 + r) * 64 + vv];
      mx = fmaxf(mx, vals[k]);
    }
    float s = 0.f;
#pragma unroll
    for (int k = 0; k < 27; ++k) {
      vals[k] = __expf(vals[k] - mx);
      s += vals[k];
    }
    float inv = 1.0f / s;
#pragma unroll
    for (int k = 0; k < 27; ++k) enc_lds[(k * 8 + r) * 64 + vv] = vals[k] * inv;
  }
  __syncthreads();

  // ---- phase 4: y[c2][r] = b_out[c2] + sum_k kern[k][r] * xo_patch[c2][k] ----
  int c2b = g * 4;  // wave g handles c2 in [4g, 4g+4)
  float accy[4][8];
#pragma unroll
  for (int i = 0; i < 4; ++i) {
    float bo = b_out[c2b + i];
#pragma unroll
    for (int r = 0; r < 8; ++r) accy[i][r] = bo;
  }
  const float* xb = xo_lds + base;
#pragma unroll 1
  for (int k = 0; k < 27; ++k) {
    int kh = k / 9;
    int r2 = k - kh * 9;
    int kw = r2 / 3;
    int kd = r2 - kw * 3;
    int off = kh * 36 + kw * 6 + kd;
    float kr[8];
#pragma unroll
    for (int r = 0; r < 8; ++r) kr[r] = enc_lds[(k * 8 + r) * 64 + v];
#pragma unroll
    for (int i = 0; i < 4; ++i) {
      float xv = xb[(c2b + i) * 216 + off];
#pragma unroll
      for (int r = 0; r < 8; ++r) accy[i][r] = fmaf(xv, kr[r], accy[i][r]);
    }
  }

  // ---- phase 5: pixel-shuffle write: fine voxel (2h+rh, 2w+rw, 2d+rd) ----
  int hh = (h0 + vz) << 1, ww = (w0 + vy) << 1, dd = (d0 + vx) << 1;
#pragma unroll
  for (int i = 0; i < 4; ++i) {
    size_t cb = ((size_t)(n * 16 + c2b + i)) << 18;  // * 64^3
#pragma unroll
    for (int rh = 0; rh < 2; ++rh)
#pragma unroll
      for (int rw = 0; rw < 2; ++rw)
#pragma unroll
        for (int rd = 0; rd < 2; ++rd)
          y[cb + (size_t)((hh + rh) << 12) + ((ww + rw) << 6) + (dd + rd)] =
              accy[i][rh * 4 + rw * 2 + rd];
  }
}

extern "C" void kernel_launch(void* const* d_in, const int* in_sizes, int n_in,
                              void* d_out, int out_size, void* d_ws, size_t ws_size,
                              hipStream_t stream) {
  const float* x      = (const float*)d_in[0];
  const float* w_down = (const float*)d_in[1];
  const float* b_down = (const float*)d_in[2];
  const float* w_enc  = (const float*)d_in[3];
  const float* b_enc  = (const float*)d_in[4];
  const float* w_out  = (const float*)d_in[5];
  const float* b_out  = (const float*)d_in[6];
  float* y = (float*)d_out;

  float* t  = (float*)d_ws;                 // 2*8*32768 floats = 2 MB
  float* xo = t + (size_t)2 * 8 * 32768;    // 2*16*32768 floats = 4 MB

  down_out_kernel<<<dim3(256), dim3(256), 0, stream>>>(x, w_down, b_down, w_out, t, xo);
  carafe_kernel<<<dim3(1024), dim3(256), 0, stream>>>(t, xo, w_enc, b_enc, b_out, y);
}

// Round 2
// 148.952 us; speedup vs baseline: 3.3173x; 3.3173x over previous
//
#include <hip/hip_runtime.h>

// CARAFE3D: C1=32, CM=8, C2=16, K=3 (k3=27), R=2 (r3=8), CK=216
// N=2, H=W=D=32, HWD=32768, out (2,16,64,64,64) fp32
//
// Round 2: enc 216x216 GEMM moved to bf16 MFMA (16x16x32).
//  - kernel 1 emits t, xo in bf16
//  - prep kernel packs w_enc to bf16 Wb[224][224] (M,K zero-padded)
//  - carafe kernel: im2col P[v][232] bf16 in LDS, 4 waves x 98 MFMA,
//    softmax on bf16 logits (fp32 math), reassembly fp32, float2 stores.

typedef short bf16x8 __attribute__((ext_vector_type(8)));
typedef float f32x4 __attribute__((ext_vector_type(4)));

#define PSTR 232  // LDS row stride (bf16 elems): 464B = 16B-aligned, 2-way-free banks

__device__ inline float b2f(unsigned short u) {
  union { unsigned int i; float f; } x;
  x.i = ((unsigned int)u) << 16;
  return x.f;
}
__device__ inline unsigned short f2b(float f) {
  union { float f; unsigned int i; } x;
  x.f = f;
  unsigned int u = x.i;
  return (unsigned short)((u + 0x7FFFu + ((u >> 16) & 1u)) >> 16);
}

// ---- kernel 1: fused 1x1 down-conv (t, bf16) + 1x1 out-conv (xo, bf16) ----
__global__ __launch_bounds__(256) void down_out_kernel(
    const float* __restrict__ x, const float* __restrict__ w_down,
    const float* __restrict__ b_down, const float* __restrict__ w_out,
    unsigned short* __restrict__ t, unsigned short* __restrict__ xo) {
  int idx = blockIdx.x * 256 + threadIdx.x;  // 0..65535
  int n = idx >> 15;
  int p = idx & 32767;
  const float* xp = x + ((size_t)n << 20) + p;
  float at[8];
  float ao[16];
#pragma unroll
  for (int m = 0; m < 8; ++m) at[m] = b_down[m];
#pragma unroll
  for (int o = 0; o < 16; ++o) ao[o] = 0.f;
#pragma unroll
  for (int c = 0; c < 32; ++c) {
    float xv = xp[(size_t)c << 15];
#pragma unroll
    for (int m = 0; m < 8; ++m) at[m] = fmaf(xv, w_down[m * 32 + c], at[m]);
#pragma unroll
    for (int o = 0; o < 16; ++o) ao[o] = fmaf(xv, w_out[o * 32 + c], ao[o]);
  }
#pragma unroll
  for (int m = 0; m < 8; ++m) t[(((size_t)n * 8 + m) << 15) + p] = f2b(at[m]);
#pragma unroll
  for (int o = 0; o < 16; ++o) xo[(((size_t)n * 16 + o) << 15) + p] = f2b(ao[o]);
}

// ---- prep: w_enc fp32 [216][216] -> bf16 Wb[224][224], zero-padded ----
__global__ __launch_bounds__(256) void prep_w_kernel(
    const float* __restrict__ w_enc, unsigned short* __restrict__ Wb) {
  int i = blockIdx.x * 256 + threadIdx.x;  // 224*224 = 50176
  if (i >= 224 * 224) return;
  int o = i / 224;
  int k = i - o * 224;
  float v = (o < 216 && k < 216) ? w_enc[o * 216 + k] : 0.f;
  Wb[i] = f2b(v);
}

// ---- main kernel: one block per 4x4x4 coarse tile, 1024 blocks ----
__global__ __launch_bounds__(256, 2) void carafe_kernel(
    const unsigned short* __restrict__ tg, const unsigned short* __restrict__ xog,
    const unsigned short* __restrict__ Wb, const float* __restrict__ b_enc,
    const float* __restrict__ b_out, float* __restrict__ y) {
  __shared__ unsigned short p_lds[64 * PSTR];    // im2col patches [v][k], 29696 B
  __shared__ unsigned short xo_lds[16 * 216];    // xo halo [c2][z6*y6*x6], 6912 B
  __shared__ unsigned short enc_lds[64 * PSTR];  // t halo early; enc/kern [v][o] late

  int b = blockIdx.x;
  int n = b >> 9;
  int tile = b & 511;
  int h0 = ((tile >> 6) & 7) << 2;
  int w0 = ((tile >> 3) & 7) << 2;
  int d0 = (tile & 7) << 2;
  int tid = threadIdx.x;

  // ---- phase 1a: t halo (8 x 6^3 bf16) into enc_lds[0..1727] ----
  for (int i = tid; i < 1728; i += 256) {
    int m = i / 216;
    int rem = i - m * 216;
    int z = rem / 36;
    int r2 = rem - z * 36;
    int yy = r2 / 6;
    int xx = r2 - yy * 6;
    int gh = h0 + z - 1, gw = w0 + yy - 1, gd = d0 + xx - 1;
    unsigned short val = 0;
    if ((unsigned)gh < 32u && (unsigned)gw < 32u && (unsigned)gd < 32u)
      val = tg[(((size_t)n * 8 + m) << 15) + (gh << 10) + (gw << 5) + gd];
    enc_lds[i] = val;
  }
  // ---- phase 1b: xo halo (16 x 6^3 bf16) ----
  for (int i = tid; i < 3456; i += 256) {
    int c = i / 216;
    int rem = i - c * 216;
    int z = rem / 36;
    int r2 = rem - z * 36;
    int yy = r2 / 6;
    int xx = r2 - yy * 6;
    int gh = h0 + z - 1, gw = w0 + yy - 1, gd = d0 + xx - 1;
    unsigned short val = 0;
    if ((unsigned)gh < 32u && (unsigned)gw < 32u && (unsigned)gd < 32u)
      val = xog[(((size_t)n * 16 + c) << 15) + (gh << 10) + (gw << 5) + gd];
    xo_lds[i] = val;
  }
  __syncthreads();

  // ---- phase 1c: build P[v][k] (k in [0,224), zero pad k>=216) ----
  // 64 voxels x 112 u32-pairs = 7168 pairs, 28 per thread
  for (int i = tid; i < 7168; i += 256) {
    int v = i / 112;
    int kk = (i - v * 112) * 2;
    int vz = v >> 4, vy = (v >> 2) & 3, vx = v & 3;
    unsigned int pk = 0;
#pragma unroll
    for (int h = 0; h < 2; ++h) {
      int k = kk + h;
      unsigned short val = 0;
      if (k < 216) {
        int m = k / 27;
        int r = k - m * 27;
        int kh = r / 9;
        int r2 = r - kh * 9;
        int kw = r2 / 3;
        int kd = r2 - kw * 3;
        val = enc_lds[m * 216 + (vz + kh) * 36 + (vy + kw) * 6 + (vx + kd)];
      }
      pk |= ((unsigned int)val) << (16 * h);
    }
    *(unsigned int*)&p_lds[v * PSTR + kk] = pk;
  }
  __syncthreads();

  // ---- phase 2: enc[o][v] = Wb(216x216) @ P + b_enc via MFMA ----
  int lane = tid & 63;
  int wv = __builtin_amdgcn_readfirstlane(tid >> 6);
  int l15 = lane & 15;
  int quad = lane >> 4;
  int mh = wv >> 1;  // M half: rows [mh*112, mh*112+112)
  int nh = wv & 1;   // N half: cols [nh*32, nh*32+32)
  {
    f32x4 acc[7][2];
#pragma unroll
    for (int i = 0; i < 7; ++i)
#pragma unroll
      for (int j = 0; j < 2; ++j) acc[i][j] = (f32x4){0.f, 0.f, 0.f, 0.f};

    const unsigned short* Arow = Wb + (mh * 112 + l15) * 224 + quad * 8;
    const unsigned short* Bp = p_lds + (nh * 32 + l15) * PSTR + quad * 8;
#pragma unroll
    for (int kt = 0; kt < 7; ++kt) {
      bf16x8 bf0 = *(const bf16x8*)(Bp + kt * 32);
      bf16x8 bf1 = *(const bf16x8*)(Bp + 16 * PSTR + kt * 32);
#pragma unroll
      for (int i = 0; i < 7; ++i) {
        bf16x8 af = *(const bf16x8*)(Arow + i * 16 * 224 + kt * 32);
        acc[i][0] = __builtin_amdgcn_mfma_f32_16x16x32_bf16(af, bf0, acc[i][0], 0, 0, 0);
        acc[i][1] = __builtin_amdgcn_mfma_f32_16x16x32_bf16(af, bf1, acc[i][1], 0, 0, 0);
      }
    }
    // epilogue: + b_enc, pack row-pairs, store bf16 to enc_lds[v][o]
#pragma unroll
    for (int i = 0; i < 7; ++i) {
      int o_base = (mh * 7 + i) * 16 + quad * 4;
#pragma unroll
      for (int r = 0; r < 4; r += 2) {
        int o = o_base + r;
        if (o < 216) {
          float be0 = b_enc[o], be1 = b_enc[o + 1];
#pragma unroll
          for (int jn = 0; jn < 2; ++jn) {
            int vv = nh * 32 + jn * 16 + l15;
            unsigned int pk = (unsigned int)f2b(acc[i][jn][r] + be0) |
                              ((unsigned int)f2b(acc[i][jn][r + 1] + be1) << 16);
            *(unsigned int*)&enc_lds[vv * PSTR + o] = pk;
          }
        }
      }
    }
  }
  __syncthreads();

  // ---- phase 3: softmax over k3=27 per (voxel, r); 512 pairs, 2/thread ----
#pragma unroll
  for (int pp = 0; pp < 2; ++pp) {
    int p = tid + pp * 256;
    int vv = p & 63;
    int r = p >> 6;
    unsigned short* e = enc_lds + vv * PSTR + r;
    float vals[27];
    float mx = -3.0e38f;
#pragma unroll
    for (int k = 0; k < 27; ++k) {
      vals[k] = b2f(e[k * 8]);
      mx = fmaxf(mx, vals[k]);
    }
    float s = 0.f;
#pragma unroll
    for (int k = 0; k < 27; ++k) {
      vals[k] = __expf(vals[k] - mx);
      s += vals[k];
    }
    float inv = 1.0f / s;
#pragma unroll
    for (int k = 0; k < 27; ++k) e[k * 8] = f2b(vals[k] * inv);
  }
  __syncthreads();

  // ---- phase 4: y[c2][r] = b_out[c2] + sum_k kern[k][r] * xo_patch[c2][k] ----
  int v = tid & 63;
  int vz = v >> 4, vy = (v >> 2) & 3, vx = v & 3;
  int base = vz * 36 + vy * 6 + vx;
  int c2b = wv * 4;
  float accy[4][8];
#pragma unroll
  for (int i = 0; i < 4; ++i) {
    float bo = b_out[c2b + i];
#pragma unroll
    for (int r = 0; r < 8; ++r) accy[i][r] = bo;
  }
  const unsigned short* kb = enc_lds + v * PSTR;
#pragma unroll
  for (int k = 0; k < 27; ++k) {
    int kh = k / 9;
    int r2 = k - kh * 9;
    int kw = r2 / 3;
    int kd = r2 - kw * 3;
    int off = base + kh * 36 + kw * 6 + kd;
    bf16x8 kr8 = *(const bf16x8*)(kb + k * 8);
    float kr[8];
#pragma unroll
    for (int r = 0; r < 8; ++r) kr[r] = b2f((unsigned short)kr8[r]);
#pragma unroll
    for (int i = 0; i < 4; ++i) {
      float xv = b2f(xo_lds[(c2b + i) * 216 + off]);
#pragma unroll
      for (int r = 0; r < 8; ++r) accy[i][r] = fmaf(xv, kr[r], accy[i][r]);
    }
  }

  // ---- phase 5: pixel-shuffle write (rd pairs -> float2 stores) ----
  int hh = (h0 + vz) << 1, ww = (w0 + vy) << 1, dd = (d0 + vx) << 1;
#pragma unroll
  for (int i = 0; i < 4; ++i) {
    size_t cb = ((size_t)(n * 16 + c2b + i)) << 18;
#pragma unroll
    for (int rh = 0; rh < 2; ++rh)
#pragma unroll
      for (int rw = 0; rw < 2; ++rw) {
        float2 val = make_float2(accy[i][rh * 4 + rw * 2], accy[i][rh * 4 + rw * 2 + 1]);
        *(float2*)&y[cb + (size_t)((hh + rh) << 12) + ((ww + rw) << 6) + dd] = val;
      }
  }
}

extern "C" void kernel_launch(void* const* d_in, const int* in_sizes, int n_in,
                              void* d_out, int out_size, void* d_ws, size_t ws_size,
                              hipStream_t stream) {
  const float* x      = (const float*)d_in[0];
  const float* w_down = (const float*)d_in[1];
  const float* b_down = (const float*)d_in[2];
  const float* w_enc  = (const float*)d_in[3];
  const float* b_enc  = (const float*)d_in[4];
  const float* w_out  = (const float*)d_in[5];
  const float* b_out  = (const float*)d_in[6];
  float* y = (float*)d_out;

  char* ws = (char*)d_ws;
  unsigned short* t  = (unsigned short*)(ws);                  // 2*8*32768*2  = 1 MB
  unsigned short* xo = (unsigned short*)(ws + (1u << 20));     // 2*16*32768*2 = 2 MB
  unsigned short* Wb = (unsigned short*)(ws + (3u << 20));     // 224*224*2 ~ 100 KB

  prep_w_kernel<<<dim3(196), dim3(256), 0, stream>>>(w_enc, Wb);
  down_out_kernel<<<dim3(256), dim3(256), 0, stream>>>(x, w_down, b_down, w_out, t, xo);
  carafe_kernel<<<dim3(1024), dim3(256), 0, stream>>>(t, xo, Wb, b_enc, b_out, y);
}

// Round 3
// 141.009 us; speedup vs baseline: 3.5042x; 1.0563x over previous
//
#include <hip/hip_runtime.h>

// CARAFE3D: C1=32, CM=8, C2=16, K=3 (k3=27), R=2 (r3=8), CK=216
// N=2, H=W=D=32, out (2,16,64,64,64) fp32
//
// Round 3: occupancy 2->4 blocks/CU (LDS 66.3->40.1 KB: enc output reuses
// p_lds, t-halo in own 3.5KB buffer), conflict-free softmax lane mapping,
// bias folded into GEMM pad column, prep fused into one setup kernel.

typedef short bf16x8 __attribute__((ext_vector_type(8)));
typedef float f32x4 __attribute__((ext_vector_type(4)));

#define PSTR 232  // LDS row stride (bf16): 464B, 16B-aligned; b128 @116dw stride tiles banks

__device__ inline float b2f(unsigned short u) {
  union { unsigned int i; float f; } x;
  x.i = ((unsigned int)u) << 16;
  return x.f;
}
__device__ inline unsigned short f2b(float f) {
  union { float f; unsigned int i; } x;
  x.f = f;
  unsigned int u = x.i;
  return (unsigned short)((u + 0x7FFFu + ((u >> 16) & 1u)) >> 16);
}
__device__ inline float2 bpair(unsigned int u) {  // packed bf16x2 -> (lo,hi) fp32
  union { unsigned int i; float f; } lo, hi;
  lo.i = u << 16;
  hi.i = u & 0xFFFF0000u;
  return make_float2(lo.f, hi.f);
}

// ---- setup: blocks [0,256): fused 1x1 convs -> t,xo bf16
//             blocks [256,452): pack w_enc+b_enc -> Wb[224][224] bf16 ----
__global__ __launch_bounds__(256) void setup_kernel(
    const float* __restrict__ x, const float* __restrict__ w_down,
    const float* __restrict__ b_down, const float* __restrict__ w_enc,
    const float* __restrict__ b_enc, const float* __restrict__ w_out,
    unsigned short* __restrict__ t, unsigned short* __restrict__ xo,
    unsigned short* __restrict__ Wb) {
  int blk = blockIdx.x;
  if (blk < 256) {
    int idx = blk * 256 + threadIdx.x;  // 0..65535
    int n = idx >> 15;
    int p = idx & 32767;
    const float* xp = x + ((size_t)n << 20) + p;
    float at[8];
    float ao[16];
#pragma unroll
    for (int m = 0; m < 8; ++m) at[m] = b_down[m];
#pragma unroll
    for (int o = 0; o < 16; ++o) ao[o] = 0.f;
#pragma unroll
    for (int c = 0; c < 32; ++c) {
      float xv = xp[(size_t)c << 15];
#pragma unroll
      for (int m = 0; m < 8; ++m) at[m] = fmaf(xv, w_down[m * 32 + c], at[m]);
#pragma unroll
      for (int o = 0; o < 16; ++o) ao[o] = fmaf(xv, w_out[o * 32 + c], ao[o]);
    }
#pragma unroll
    for (int m = 0; m < 8; ++m) t[(((size_t)n * 8 + m) << 15) + p] = f2b(at[m]);
#pragma unroll
    for (int o = 0; o < 16; ++o) xo[(((size_t)n * 16 + o) << 15) + p] = f2b(ao[o]);
  } else {
    int i = (blk - 256) * 256 + threadIdx.x;  // 224*224 = 50176
    if (i < 224 * 224) {
      int o = i / 224;
      int k = i - o * 224;
      float v = 0.f;
      if (o < 216) {
        if (k < 216) v = w_enc[o * 216 + k];
        else if (k == 216) v = b_enc[o];  // bias via pad column (P[.][216]=1)
      }
      Wb[i] = f2b(v);
    }
  }
}

// ---- main: one block per 4x4x4 coarse tile, 1024 blocks, 4 blocks/CU ----
__global__ __launch_bounds__(256, 4) void carafe_kernel(
    const unsigned short* __restrict__ tg, const unsigned short* __restrict__ xog,
    const unsigned short* __restrict__ Wb, const float* __restrict__ b_out,
    float* __restrict__ y) {
  __shared__ unsigned short t_lds[1728];                        // t halo, 3456 B
  __shared__ __align__(16) unsigned short p_lds[64 * PSTR];     // P; then kern logits
  __shared__ unsigned short xo_lds[16 * 216];                   // xo halo, 6912 B

  int b = blockIdx.x;
  int n = b >> 9;
  int tile = b & 511;
  int h0 = ((tile >> 6) & 7) << 2;
  int w0 = ((tile >> 3) & 7) << 2;
  int d0 = (tile & 7) << 2;
  int tid = threadIdx.x;

  // ---- phase 1a: t halo (8 x 6^3) ----
  for (int i = tid; i < 1728; i += 256) {
    int m = i / 216;
    int rem = i - m * 216;
    int z = rem / 36;
    int r2 = rem - z * 36;
    int yy = r2 / 6;
    int xx = r2 - yy * 6;
    int gh = h0 + z - 1, gw = w0 + yy - 1, gd = d0 + xx - 1;
    unsigned short val = 0;
    if ((unsigned)gh < 32u && (unsigned)gw < 32u && (unsigned)gd < 32u)
      val = tg[(((size_t)n * 8 + m) << 15) + (gh << 10) + (gw << 5) + gd];
    t_lds[i] = val;
  }
  // ---- phase 1b: xo halo (16 x 6^3) ----
  for (int i = tid; i < 3456; i += 256) {
    int c = i / 216;
    int rem = i - c * 216;
    int z = rem / 36;
    int r2 = rem - z * 36;
    int yy = r2 / 6;
    int xx = r2 - yy * 6;
    int gh = h0 + z - 1, gw = w0 + yy - 1, gd = d0 + xx - 1;
    unsigned short val = 0;
    if ((unsigned)gh < 32u && (unsigned)gw < 32u && (unsigned)gd < 32u)
      val = xog[(((size_t)n * 16 + c) << 15) + (gh << 10) + (gw << 5) + gd];
    xo_lds[i] = val;
  }
  __syncthreads();

  // ---- phase 1c: im2col P[v][k]; k=216 -> 1.0 (bias column), k>216 -> 0 ----
  for (int i = tid; i < 7168; i += 256) {
    int v = i / 112;
    int kk = (i - v * 112) * 2;
    int vz = v >> 4, vy = (v >> 2) & 3, vx = v & 3;
    unsigned int pk = 0;
#pragma unroll
    for (int h = 0; h < 2; ++h) {
      int k = kk + h;
      unsigned short val = 0;
      if (k < 216) {
        int m = k / 27;
        int r = k - m * 27;
        int kh = r / 9;
        int r2 = r - kh * 9;
        int kw = r2 / 3;
        int kd = r2 - kw * 3;
        val = t_lds[m * 216 + (vz + kh) * 36 + (vy + kw) * 6 + (vx + kd)];
      } else if (k == 216) {
        val = 0x3F80;  // bf16(1.0)
      }
      pk |= ((unsigned int)val) << (16 * h);
    }
    *(unsigned int*)&p_lds[v * PSTR + kk] = pk;
  }
  __syncthreads();

  int lane = tid & 63;
  int wv = __builtin_amdgcn_readfirstlane(tid >> 6);
  int l15 = lane & 15;
  int quad = lane >> 4;
  int mh = wv >> 1;  // M half: rows [mh*112, +112)
  int nh = wv & 1;   // N half: cols [nh*32, +32)

  // ---- phase 2: enc = Wb(216x224) @ P^T via 16x16x32 bf16 MFMA ----
  f32x4 acc[7][2];
#pragma unroll
  for (int i = 0; i < 7; ++i)
#pragma unroll
    for (int j = 0; j < 2; ++j) acc[i][j] = (f32x4){0.f, 0.f, 0.f, 0.f};
  {
    const unsigned short* Arow = Wb + (mh * 112 + l15) * 224 + quad * 8;
    const unsigned short* Bp = p_lds + (nh * 32 + l15) * PSTR + quad * 8;
#pragma unroll
    for (int kt = 0; kt < 7; ++kt) {
      bf16x8 bf0 = *(const bf16x8*)(Bp + kt * 32);
      bf16x8 bf1 = *(const bf16x8*)(Bp + 16 * PSTR + kt * 32);
#pragma unroll
      for (int i = 0; i < 7; ++i) {
        bf16x8 af = *(const bf16x8*)(Arow + i * 16 * 224 + kt * 32);
        acc[i][0] = __builtin_amdgcn_mfma_f32_16x16x32_bf16(af, bf0, acc[i][0], 0, 0, 0);
        acc[i][1] = __builtin_amdgcn_mfma_f32_16x16x32_bf16(af, bf1, acc[i][1], 0, 0, 0);
      }
    }
  }
  __syncthreads();  // all MFMA reads of p_lds complete -> safe to overwrite

  // ---- phase 2b: store enc logits bf16 into p_lds[v][o] ----
#pragma unroll
  for (int i = 0; i < 7; ++i) {
    int o_base = (mh * 7 + i) * 16 + quad * 4;
#pragma unroll
    for (int r = 0; r < 4; r += 2) {
      int o = o_base + r;
      if (o < 216) {
#pragma unroll
        for (int jn = 0; jn < 2; ++jn) {
          int vv = nh * 32 + jn * 16 + l15;
          unsigned int pk = (unsigned int)f2b(acc[i][jn][r]) |
                            ((unsigned int)f2b(acc[i][jn][r + 1]) << 16);
          *(unsigned int*)&p_lds[vv * PSTR + o] = pk;
        }
      }
    }
  }
  __syncthreads();

  // ---- phase 3: softmax over k3=27 per (voxel,r); lane map r-fast => conflict-free ----
#pragma unroll
  for (int pp = 0; pp < 2; ++pp) {
    int p = tid + pp * 256;  // 0..511
    int r = p & 7;
    int vv = p >> 3;
    unsigned short* e = p_lds + vv * PSTR + r;
    float vals[27];
    float mx = -3.0e38f;
#pragma unroll
    for (int k = 0; k < 27; ++k) {
      vals[k] = b2f(e[k * 8]);
      mx = fmaxf(mx, vals[k]);
    }
    float s = 0.f;
#pragma unroll
    for (int k = 0; k < 27; ++k) {
      vals[k] = __expf(vals[k] - mx);
      s += vals[k];
    }
    float inv = 1.0f / s;
#pragma unroll
    for (int k = 0; k < 27; ++k) e[k * 8] = f2b(vals[k] * inv);
  }
  __syncthreads();

  // ---- phase 4: y[c2][r] = b_out[c2] + sum_k kern[k][r]*xo_patch[c2][k] ----
  int v = tid & 63;
  int vz = v >> 4, vy = (v >> 2) & 3, vx = v & 3;
  int base = vz * 36 + vy * 6 + vx;
  int c2b = wv * 4;
  float2 accy[4][4];
#pragma unroll
  for (int i = 0; i < 4; ++i) {
    float bo = b_out[c2b + i];
#pragma unroll
    for (int j = 0; j < 4; ++j) accy[i][j] = make_float2(bo, bo);
  }
  const unsigned short* kb = p_lds + v * PSTR;
#pragma unroll
  for (int k = 0; k < 27; ++k) {
    int kh = k / 9;
    int r2 = k - kh * 9;
    int kw = r2 / 3;
    int kd = r2 - kw * 3;
    int off = base + kh * 36 + kw * 6 + kd;
    uint4 kw4 = *(const uint4*)(kb + k * 8);
    float2 kr[4];
    kr[0] = bpair(kw4.x);
    kr[1] = bpair(kw4.y);
    kr[2] = bpair(kw4.z);
    kr[3] = bpair(kw4.w);
#pragma unroll
    for (int i = 0; i < 4; ++i) {
      float xv = b2f(xo_lds[(c2b + i) * 216 + off]);
#pragma unroll
      for (int j = 0; j < 4; ++j) {
        accy[i][j].x = fmaf(xv, kr[j].x, accy[i][j].x);
        accy[i][j].y = fmaf(xv, kr[j].y, accy[i][j].y);
      }
    }
  }

  // ---- phase 5: pixel-shuffle write, float2 stores ----
  int hh = (h0 + vz) << 1, ww = (w0 + vy) << 1, dd = (d0 + vx) << 1;
#pragma unroll
  for (int i = 0; i < 4; ++i) {
    size_t cb = ((size_t)(n * 16 + c2b + i)) << 18;
#pragma unroll
    for (int rh = 0; rh < 2; ++rh)
#pragma unroll
      for (int rw = 0; rw < 2; ++rw)
        *(float2*)&y[cb + (size_t)((hh + rh) << 12) + ((ww + rw) << 6) + dd] =
            accy[i][rh * 2 + rw];
  }
}

extern "C" void kernel_launch(void* const* d_in, const int* in_sizes, int n_in,
                              void* d_out, int out_size, void* d_ws, size_t ws_size,
                              hipStream_t stream) {
  const float* x      = (const float*)d_in[0];
  const float* w_down = (const float*)d_in[1];
  const float* b_down = (const float*)d_in[2];
  const float* w_enc  = (const float*)d_in[3];
  const float* b_enc  = (const float*)d_in[4];
  const float* w_out  = (const float*)d_in[5];
  const float* b_out  = (const float*)d_in[6];
  float* y = (float*)d_out;

  char* ws = (char*)d_ws;
  unsigned short* t  = (unsigned short*)(ws);                  // 1 MB
  unsigned short* xo = (unsigned short*)(ws + (1u << 20));     // 2 MB
  unsigned short* Wb = (unsigned short*)(ws + (3u << 20));     // ~100 KB

  setup_kernel<<<dim3(452), dim3(256), 0, stream>>>(x, w_down, b_down, w_enc,
                                                    b_enc, w_out, t, xo, Wb);
  carafe_kernel<<<dim3(1024), dim3(256), 0, stream>>>(t, xo, Wb, b_out, y);
}

// Round 4
// 115.661 us; speedup vs baseline: 4.2722x; 1.2192x over previous
//
#include <hip/hip_runtime.h>

// CARAFE3D: C1=32, CM=8, C2=16, K=3 (k3=27), R=2 (r3=8), CK=216
// N=2, H=W=D=32, out (2,16,64,64,64) fp32
//
// Round 4: XCD write-combine block swizzle (4 d-tiles per 128B line share an
// XCD); halo-padded global t/xo layouts -> vectorized staging, no bounds
// checks; xo channel-pair interleaved (u32 reads serve 2 channels); im2col
// with compile-const offsets; u32-paired softmax; v_pk_fma_f32 phase 4.

typedef short bf16x8 __attribute__((ext_vector_type(8)));
typedef float f32x4 __attribute__((ext_vector_type(4)));
typedef float v2f __attribute__((ext_vector_type(2)));

#define PSTR 232    // P row stride in bf16 (464 B, 16B-aligned, 2-way banks)
#define PSTRD 116   // same in dwords
#define MSP 41616   // padded per-channel volume: 34*34*36
#define HSP 1224    // padded h stride: 34*36
#define WSP 36      // padded w stride

__device__ inline float b2f(unsigned short u) {
  union { unsigned int i; float f; } x;
  x.i = ((unsigned int)u) << 16;
  return x.f;
}
__device__ inline unsigned short f2b(float f) {
  union { float f; unsigned int i; } x;
  x.f = f;
  unsigned int u = x.i;
  return (unsigned short)((u + 0x7FFFu + ((u >> 16) & 1u)) >> 16);
}
__device__ inline v2f b2f2(unsigned int u) {  // packed bf16x2 -> v2f
  union { unsigned int i; float f; } lo, hi;
  lo.i = u << 16;
  hi.i = u & 0xFFFF0000u;
  return (v2f){lo.f, hi.f};
}

// ---- zero kernel: clears padded t + xo buffers (halo cells stay 0) ----
__global__ __launch_bounds__(256) void zero_ws(uint4* __restrict__ p, int n4) {
  int i = blockIdx.x * 256 + threadIdx.x;
  if (i < n4) p[i] = make_uint4(0u, 0u, 0u, 0u);
}

// ---- setup: blocks [0,256): fused 1x1 convs -> padded t (bf16), padded
//      xo (channel-pair-interleaved u32); blocks [256,452): Wb pack ----
__global__ __launch_bounds__(256) void setup_kernel(
    const float* __restrict__ x, const float* __restrict__ w_down,
    const float* __restrict__ b_down, const float* __restrict__ w_enc,
    const float* __restrict__ b_enc, const float* __restrict__ w_out,
    unsigned short* __restrict__ t, unsigned int* __restrict__ xo32,
    unsigned short* __restrict__ Wb) {
  int blk = blockIdx.x;
  if (blk < 256) {
    int idx = blk * 256 + threadIdx.x;  // 0..65535
    int n = idx >> 15, p = idx & 32767;
    int h = p >> 10, w = (p >> 5) & 31, d = p & 31;
    const float* xp = x + ((size_t)n << 20) + p;
    float at[8], ao[16];
#pragma unroll
    for (int m = 0; m < 8; ++m) at[m] = b_down[m];
#pragma unroll
    for (int o = 0; o < 16; ++o) ao[o] = 0.f;
#pragma unroll
    for (int c = 0; c < 32; ++c) {
      float xv = xp[(size_t)c << 15];
#pragma unroll
      for (int m = 0; m < 8; ++m) at[m] = fmaf(xv, w_down[m * 32 + c], at[m]);
#pragma unroll
      for (int o = 0; o < 16; ++o) ao[o] = fmaf(xv, w_out[o * 32 + c], ao[o]);
    }
    size_t sp = (size_t)(h + 1) * HSP + (size_t)(w + 1) * WSP + (d + 2);
#pragma unroll
    for (int m = 0; m < 8; ++m) t[(size_t)(n * 8 + m) * MSP + sp] = f2b(at[m]);
#pragma unroll
    for (int cp = 0; cp < 8; ++cp)
      xo32[(size_t)(n * 8 + cp) * MSP + sp] =
          (unsigned int)f2b(ao[2 * cp]) | ((unsigned int)f2b(ao[2 * cp + 1]) << 16);
  } else {
    int i = (blk - 256) * 256 + threadIdx.x;  // 224*224 = 50176
    if (i < 224 * 224) {
      int o = i / 224;
      int k = i - o * 224;
      float v = 0.f;
      if (o < 216) {
        if (k < 216) v = w_enc[o * 216 + k];
        else if (k == 216) v = b_enc[o];  // bias via pad column (P[.][216]=1)
      }
      Wb[i] = f2b(v);
    }
  }
}

// ---- main: one block per 4x4x4 coarse tile, 1024 blocks, 4 blocks/CU ----
__global__ __launch_bounds__(256, 4) void carafe_kernel(
    const unsigned short* __restrict__ tg, const unsigned int* __restrict__ xog,
    const unsigned short* __restrict__ Wb, const float* __restrict__ b_out,
    float* __restrict__ y) {
  __shared__ __align__(16) unsigned short p_lds[64 * PSTR];  // P; then logits/kern
  __shared__ __align__(16) unsigned short t_lds[1728];       // t halo [m][z][y][6]
  __shared__ __align__(16) unsigned int xo_lds[1728];        // xo halo [cp][216] u32

  unsigned int* p32 = (unsigned int*)p_lds;
  unsigned int* t32 = (unsigned int*)t_lds;

  // XCD write-combine swizzle: the 4 d-tiles covering one 128B output line
  // get identical blockIdx%8 (same XCD) -> full-line writes.
  int pb = blockIdx.x;
  int G = ((pb >> 5) << 3) | (pb & 7);  // 0..255
  int q = (pb >> 3) & 3;
  int n = G >> 7;
  int h0 = ((G >> 4) & 7) << 2;
  int w0 = ((G >> 1) & 7) << 2;
  int d0 = ((G & 1) * 4 + q) << 2;
  int tid = threadIdx.x;

  // ---- phase 1a: t halo rows (8m x 6z x 6y), vector loads, no bounds ----
  for (int rr = tid; rr < 288; rr += 256) {
    int m = rr / 36;
    int rem = rr - m * 36;
    int z = rem / 6;
    int yy = rem - z * 6;
    size_t gsrc = (size_t)(n * 8 + m) * MSP + (size_t)(h0 + z) * HSP +
                  (size_t)(w0 + yy) * WSP + d0;  // phys d0 = logical d0-2
    uint2 l0 = *(const uint2*)(tg + gsrc);
    uint2 l1 = *(const uint2*)(tg + gsrc + 4);
    unsigned a = l0.x, b = l0.y, c = l1.x, e = l1.y;  // shorts s0..s7
    int dst = m * 108 + z * 18 + yy * 3;              // dword idx, row = s1..s6
    t32[dst] = (a >> 16) | (b << 16);
    t32[dst + 1] = (b >> 16) | (c << 16);
    t32[dst + 2] = (c >> 16) | (e << 16);
  }
  // ---- phase 1b: xo halo rows (8cp x 6z x 6y), u32-pair rows ----
  for (int rr = tid; rr < 288; rr += 256) {
    int cp = rr / 36;
    int rem = rr - cp * 36;
    int z = rem / 6;
    int yy = rem - z * 6;
    size_t gsrc = (size_t)(n * 8 + cp) * MSP + (size_t)(h0 + z) * HSP +
                  (size_t)(w0 + yy) * WSP + d0;
    uint4 q0 = *(const uint4*)(xog + gsrc);
    uint4 q1 = *(const uint4*)(xog + gsrc + 4);
    int dst = cp * 216 + z * 36 + yy * 6;  // u32 idx, keep logical d0-1..d0+4
    *(uint2*)&xo_lds[dst] = make_uint2(q0.y, q0.z);
    *(uint2*)&xo_lds[dst + 2] = make_uint2(q0.w, q1.x);
    *(uint2*)&xo_lds[dst + 4] = make_uint2(q1.y, q1.z);
  }
  __syncthreads();

  int lane = tid & 63;
  int wv = __builtin_amdgcn_readfirstlane(tid >> 6);

  // ---- phase 1c: im2col P[v][k], lane = (vlocal, kq): 2 m-planes each,
  //      all spatial offsets compile-const ----
  {
    int vloc = lane >> 2, kq = lane & 3;
    int v = wv * 16 + vloc;
    int vz = v >> 4, vy = (v >> 2) & 3, vx = v & 3;
    int base2 = vz * 36 + vy * 6 + vx;
    unsigned short s[54];
#pragma unroll
    for (int mi = 0; mi < 2; ++mi) {
      int srcb = base2 + (kq * 2 + mi) * 216;
#pragma unroll
      for (int kh = 0; kh < 3; ++kh)
#pragma unroll
        for (int kw = 0; kw < 3; ++kw)
#pragma unroll
          for (int kd = 0; kd < 3; ++kd)
            s[mi * 27 + kh * 9 + kw * 3 + kd] = t_lds[srcb + kh * 36 + kw * 6 + kd];
    }
    unsigned int* pr = p32 + v * PSTRD + kq * 27;
#pragma unroll
    for (int j = 0; j < 27; ++j)
      pr[j] = (unsigned int)s[2 * j] | ((unsigned int)s[2 * j + 1] << 16);
    if (tid < 64) {  // bias column k=216 -> 1.0, k=217..223 -> 0
      unsigned int* r = p32 + tid * PSTRD;
      r[108] = 0x3F80u;
      r[109] = 0u; r[110] = 0u; r[111] = 0u;
    }
  }
  __syncthreads();

  int l15 = lane & 15;
  int quad = lane >> 4;
  int mh = wv >> 1;  // M half: rows [mh*112, +112)
  int nh = wv & 1;   // N half: cols [nh*32, +32)

  // ---- phase 2: enc = Wb(216x224) @ P^T via 16x16x32 bf16 MFMA ----
  f32x4 acc[7][2];
#pragma unroll
  for (int i = 0; i < 7; ++i)
#pragma unroll
    for (int j = 0; j < 2; ++j) acc[i][j] = (f32x4){0.f, 0.f, 0.f, 0.f};
  {
    const unsigned short* Arow = Wb + (mh * 112 + l15) * 224 + quad * 8;
    const unsigned short* Bp = p_lds + (nh * 32 + l15) * PSTR + quad * 8;
#pragma unroll
    for (int kt = 0; kt < 7; ++kt) {
      bf16x8 bf0 = *(const bf16x8*)(Bp + kt * 32);
      bf16x8 bf1 = *(const bf16x8*)(Bp + 16 * PSTR + kt * 32);
#pragma unroll
      for (int i = 0; i < 7; ++i) {
        bf16x8 af = *(const bf16x8*)(Arow + i * 16 * 224 + kt * 32);
        acc[i][0] = __builtin_amdgcn_mfma_f32_16x16x32_bf16(af, bf0, acc[i][0], 0, 0, 0);
        acc[i][1] = __builtin_amdgcn_mfma_f32_16x16x32_bf16(af, bf1, acc[i][1], 0, 0, 0);
      }
    }
  }
  __syncthreads();  // all MFMA reads of p_lds done -> safe to overwrite

  // ---- phase 2b: store logits bf16 into p_lds[v][o], b64 stores ----
#pragma unroll
  for (int i = 0; i < 7; ++i) {
    int o = (mh * 7 + i) * 16 + quad * 4;
    if (o < 216) {
#pragma unroll
      for (int jn = 0; jn < 2; ++jn) {
        int vv = nh * 32 + jn * 16 + l15;
        unsigned lo = (unsigned)f2b(acc[i][jn][0]) | ((unsigned)f2b(acc[i][jn][1]) << 16);
        unsigned hi = (unsigned)f2b(acc[i][jn][2]) | ((unsigned)f2b(acc[i][jn][3]) << 16);
        *(uint2*)&p_lds[vv * PSTR + o] = make_uint2(lo, hi);
      }
    }
  }
  __syncthreads();

  // ---- phase 3: softmax over k3=27, thread = (voxel, r-pair), u32 I/O ----
  {
    int vv = tid >> 2, rp = tid & 3;
    unsigned int* e = p32 + vv * PSTRD + rp;
    float v0[27], v1[27];
    float mx0 = -3.0e38f, mx1 = -3.0e38f;
#pragma unroll
    for (int k = 0; k < 27; ++k) {
      v2f f = b2f2(e[k * 4]);
      v0[k] = f.x; v1[k] = f.y;
      mx0 = fmaxf(mx0, f.x);
      mx1 = fmaxf(mx1, f.y);
    }
    float s0 = 0.f, s1 = 0.f;
#pragma unroll
    for (int k = 0; k < 27; ++k) {
      v0[k] = __expf(v0[k] - mx0);
      v1[k] = __expf(v1[k] - mx1);
      s0 += v0[k];
      s1 += v1[k];
    }
    float i0 = 1.0f / s0, i1 = 1.0f / s1;
#pragma unroll
    for (int k = 0; k < 27; ++k)
      e[k * 4] = (unsigned)f2b(v0[k] * i0) | ((unsigned)f2b(v1[k] * i1) << 16);
  }
  __syncthreads();

  // ---- phase 4: y[c2][r] = b_out[c2] + sum_k kern[k][r]*xo[c2][k], pk-fma ----
  int v4 = lane;
  int vz = v4 >> 4, vy = (v4 >> 2) & 3, vx = v4 & 3;
  int base = vz * 36 + vy * 6 + vx;
  int cpb = wv * 2;  // channels 4wv..4wv+3 = pairs {2wv, 2wv+1}
  v2f accy[4][4];    // [c2 offset][r-pair]
#pragma unroll
  for (int i = 0; i < 4; ++i) {
    float bo = b_out[wv * 4 + i];
#pragma unroll
    for (int j = 0; j < 4; ++j) accy[i][j] = (v2f){bo, bo};
  }
  const unsigned short* kb = p_lds + v4 * PSTR;
#pragma unroll
  for (int kh = 0; kh < 3; ++kh)
#pragma unroll
    for (int kw = 0; kw < 3; ++kw)
#pragma unroll
      for (int kd = 0; kd < 3; ++kd) {
        int k = kh * 9 + kw * 3 + kd;
        int off = base + kh * 36 + kw * 6 + kd;
        uint4 kw4 = *(const uint4*)(kb + k * 8);
        v2f kr[4];
        kr[0] = b2f2(kw4.x);
        kr[1] = b2f2(kw4.y);
        kr[2] = b2f2(kw4.z);
        kr[3] = b2f2(kw4.w);
        v2f x0 = b2f2(xo_lds[(cpb + 0) * 216 + off]);
        v2f x1 = b2f2(xo_lds[(cpb + 1) * 216 + off]);
        float xv[4] = {x0.x, x0.y, x1.x, x1.y};
#pragma unroll
        for (int i = 0; i < 4; ++i) {
          v2f xs = (v2f){xv[i], xv[i]};
#pragma unroll
          for (int j = 0; j < 4; ++j)
            accy[i][j] = __builtin_elementwise_fma(xs, kr[j], accy[i][j]);
        }
      }

  // ---- phase 5: pixel-shuffle write, float2 stores ----
  int hh = (h0 + vz) << 1, ww = (w0 + vy) << 1, dd = (d0 + vx) << 1;
#pragma unroll
  for (int i = 0; i < 4; ++i) {
    size_t cb = ((size_t)(n * 16 + wv * 4 + i)) << 18;
#pragma unroll
    for (int rh = 0; rh < 2; ++rh)
#pragma unroll
      for (int rw = 0; rw < 2; ++rw) {
        v2f a = accy[i][rh * 2 + rw];
        *(float2*)&y[cb + (size_t)((hh + rh) << 12) + ((ww + rw) << 6) + dd] =
            make_float2(a.x, a.y);
      }
  }
}

extern "C" void kernel_launch(void* const* d_in, const int* in_sizes, int n_in,
                              void* d_out, int out_size, void* d_ws, size_t ws_size,
                              hipStream_t stream) {
  const float* x      = (const float*)d_in[0];
  const float* w_down = (const float*)d_in[1];
  const float* b_down = (const float*)d_in[2];
  const float* w_enc  = (const float*)d_in[3];
  const float* b_enc  = (const float*)d_in[4];
  const float* w_out  = (const float*)d_in[5];
  const float* b_out  = (const float*)d_in[6];
  float* y = (float*)d_out;

  char* ws = (char*)d_ws;
  // padded t: 2*8*41616 bf16 = 2,663,424 B; padded xo: 2*8*41616 u32 = 2,663,424 B
  unsigned short* t    = (unsigned short*)(ws);
  unsigned int*   xo32 = (unsigned int*)(ws + 2663424);
  unsigned short* Wb   = (unsigned short*)(ws + 5326848);  // 224*224*2 B

  int n4 = (2 * 2663424) / 16;  // 332928 uint4 covering t+xo
  zero_ws<<<dim3((n4 + 255) / 256), dim3(256), 0, stream>>>((uint4*)ws, n4);
  setup_kernel<<<dim3(452), dim3(256), 0, stream>>>(x, w_down, b_down, w_enc,
                                                    b_enc, w_out, t, xo32, Wb);
  carafe_kernel<<<dim3(1024), dim3(256), 0, stream>>>(t, xo32, Wb, b_out, y);
}